// Round 2
// baseline (307.517 us; speedup 1.0000x reference)
//
#include <hip/hip_runtime.h>
#include <math.h>

// Problem constants (fixed by the reference).
#define Bsz 64
#define Ssz 14
#define Isz 32
#define Csz 10
#define Psz 4
#define Dsz 16
#define Nsz (Ssz*Ssz*Isz)   // 6272
#define EPSF 1e-9f

#define NCH 8               // n-chunks for the M-step split
#define CHUNK 784           // 8*784 == 6272 exactly

// ---------------------------------------------------------------------------
// M-step partial kernel: one block per (b,c,chunk). Threads stride over the
// chunk's n-range accumulating
//   S0 = sum_n w_n,  S1[d] = sum_n w_n*v[d],  S2[d] = sum_n w_n*v[d]^2
// with w_n = rr_p[b,c,n] (or act[n]/C on the uniform first iteration), and
// v = vote recomputed on the fly (pose[n] 4x4 @ W[i,c] + coords).
// Wave butterfly + cross-wave LDS reduce -> 33 partials per block.
// Grid x = bc (fast axis) so all 10 c-blocks reading one pose chunk are
// co-resident -> L2/L3 absorbs the c-re-read (was 107 MB HBM fetch).
// ---------------------------------------------------------------------------
__global__ __launch_bounds__(256) void m_partial_kernel(
    const float* __restrict__ pose,     // [B][N][16]
    const float* __restrict__ act,      // [B][N]
    const float* __restrict__ w,        // [I][C][16]
    const float* __restrict__ rr_p,     // [B][C][N]
    float* __restrict__ partials,       // [B*C][NCH][33]
    int uniform)
{
    const int bc = blockIdx.x;
    const int chunk = blockIdx.y;
    const int b = bc / Csz, c = bc % Csz;
    const int tid = threadIdx.x;

    __shared__ float Wc[Isz*17];        // W[i][c][qr], stride 17 -> conflict-free
    __shared__ float red[4][33];

    for (int t = tid; t < Isz*Dsz; t += 256) {
        int i = t >> 4, qr = t & 15;
        Wc[i*17 + qr] = w[(i*Csz + c)*Dsz + qr];
    }
    __syncthreads();

    float s0 = 0.f;
    float s1[Dsz], s2[Dsz];
#pragma unroll
    for (int d = 0; d < Dsz; ++d) { s1[d] = 0.f; s2[d] = 0.f; }

    const float* poseb = pose + (size_t)b * Nsz * Dsz;
    const float* actb  = act  + (size_t)b * Nsz;
    const float* rrb   = rr_p + ((size_t)b * Csz + c) * Nsz;

    const int n_end = chunk*CHUNK + CHUNK;
    for (int n = chunk*CHUNK + tid; n < n_end; n += 256) {
        const float4* pp = reinterpret_cast<const float4*>(poseb + (size_t)n * Dsz);
        float4 a0 = pp[0], a1 = pp[1], a2 = pp[2], a3 = pp[3];
        float p[16] = {a0.x,a0.y,a0.z,a0.w, a1.x,a1.y,a1.z,a1.w,
                       a2.x,a2.y,a2.z,a2.w, a3.x,a3.y,a3.z,a3.w};
        int i  = n & (Isz-1);
        int hw = n >> 5;
        int wcol = hw % Ssz, hrow = hw / Ssz;
        float wgt = uniform ? (actb[n] * (1.0f/Csz)) : rrb[n];

        const float* Wi = &Wc[i*17];
        float v[16];
#pragma unroll
        for (int pr = 0; pr < 4; ++pr) {
#pragma unroll
            for (int r = 0; r < 4; ++r) {
                v[pr*4+r] = p[pr*4+0]*Wi[0*4+r] + p[pr*4+1]*Wi[1*4+r]
                          + p[pr*4+2]*Wi[2*4+r] + p[pr*4+3]*Wi[3*4+r];
            }
        }
        v[0] += (hrow + 0.5f) * (1.0f/Ssz);   // coordinate addition (h on elem 0)
        v[1] += (wcol + 0.5f) * (1.0f/Ssz);   // (w on elem 1)

        s0 += wgt;
#pragma unroll
        for (int d = 0; d < Dsz; ++d) {
            float wv = wgt * v[d];
            s1[d] += wv;
            s2[d] += wv * v[d];
        }
    }

    // 64-lane wave butterfly reduction
#pragma unroll
    for (int m = 32; m >= 1; m >>= 1) {
        s0 += __shfl_xor(s0, m);
#pragma unroll
        for (int d = 0; d < Dsz; ++d) {
            s1[d] += __shfl_xor(s1[d], m);
            s2[d] += __shfl_xor(s2[d], m);
        }
    }
    const int wave = tid >> 6, lane = tid & 63;
    if (lane == 0) {
        red[wave][0] = s0;
#pragma unroll
        for (int d = 0; d < Dsz; ++d) { red[wave][1+d] = s1[d]; red[wave][17+d] = s2[d]; }
    }
    __syncthreads();

    if (tid < 33) {
        float v4 = red[0][tid] + red[1][tid] + red[2][tid] + red[3][tid];
        partials[((size_t)bc*NCH + chunk)*33 + tid] = v4;
    }
}

// ---------------------------------------------------------------------------
// M finalize: one thread per (b,c). Sum the NCH chunk-partials, compute
// mean/var/stdv/cost/o_act, write 33 params for the E-step; final iteration
// also writes the kernel outputs.
// ---------------------------------------------------------------------------
__global__ __launch_bounds__(64) void m_finalize_kernel(
    const float* __restrict__ partials, // [B*C][NCH][33]
    const float* __restrict__ beta_v,   // [C]
    const float* __restrict__ beta_a,   // [C]
    float* __restrict__ params,         // [B*C][33] : mean[16], invdenom[16], K
    float* __restrict__ out,            // [B][C][16] then [B][C]
    float inv_temp, int final_it)
{
    const int bc = blockIdx.x * 64 + threadIdx.x;
    if (bc >= Bsz*Csz) return;
    const int b = bc / Csz, c = bc % Csz;

    float S[33];
#pragma unroll
    for (int j = 0; j < 33; ++j) S[j] = 0.f;
    const float* pb = partials + (size_t)bc * NCH * 33;
    for (int ch = 0; ch < NCH; ++ch)
#pragma unroll
        for (int j = 0; j < 33; ++j) S[j] += pb[ch*33 + j];

    float S0 = S[0];
    float sumlog = 0.f;
    float mean[16], invd[16];
#pragma unroll
    for (int d = 0; d < Dsz; ++d) {
        float S1 = S[1+d], S2 = S[17+d];
        float mn  = S1 / S0;
        float var = fmaxf(S2 / S0 - mn*mn, 0.f);   // one-pass variance, clamped
        float stdv = sqrtf(var);
        sumlog += logf(stdv + EPSF);
        mean[d] = mn;
        invd[d] = 1.f / (2.f*var + EPSF);
    }
    float cost = S0 * (16.f * beta_v[c] + sumlog);
    float oact = 1.f / (1.f + expf(-inv_temp * (beta_a[c] - cost)));

    float* prm = params + (size_t)bc * 33;
#pragma unroll
    for (int d = 0; d < Dsz; ++d) { prm[d] = mean[d]; prm[16+d] = invd[d]; }
    prm[32] = logf(oact + EPSF) - sumlog;   // K[c] for the E-step

    if (final_it) {
        float* om = out + (size_t)bc * Dsz;
#pragma unroll
        for (int d = 0; d < Dsz; ++d) om[d] = mean[d];
        out[Bsz*Csz*Dsz + bc] = oact;
    }
}

// ---------------------------------------------------------------------------
// E-step kernel (unchanged this round): thread per (b,n). Recompute all C*16
// votes, zz[c] = K[c] - sum_d (v-mean)^2*invdenom, softmax over c, write
// rr_p[b][c][n] = softmax(zz)[c]*act[n].
// ---------------------------------------------------------------------------
__global__ __launch_bounds__(256) void e_step_kernel(
    const float* __restrict__ pose,     // [B][N][16]
    const float* __restrict__ act,      // [B][N]
    const float* __restrict__ w,        // [I][C][16]
    const float* __restrict__ params,   // [B*C][33]
    float* __restrict__ rr_p)           // [B][C][N]
{
    const int b = blockIdx.y;
    const int tid = threadIdx.x;
    const int n = blockIdx.x * 256 + tid;

    __shared__ float Wl[Isz*161];       // W[i][c*16+qr], stride 161 -> conflict-free
    __shared__ float prm[Csz*33];

    for (int t = tid; t < Isz*Csz*Dsz; t += 256) {
        int i = t / (Csz*Dsz);
        int rest = t - i*(Csz*Dsz);
        Wl[i*161 + rest] = w[t];
    }
    for (int t = tid; t < Csz*33; t += 256)
        prm[t] = params[(size_t)b*Csz*33 + t];
    __syncthreads();

    if (n >= Nsz) return;

    const float4* pp = reinterpret_cast<const float4*>(pose + ((size_t)b * Nsz + n) * Dsz);
    float4 a0 = pp[0], a1 = pp[1], a2 = pp[2], a3 = pp[3];
    float p[16] = {a0.x,a0.y,a0.z,a0.w, a1.x,a1.y,a1.z,a1.w,
                   a2.x,a2.y,a2.z,a2.w, a3.x,a3.y,a3.z,a3.w};
    float a = act[(size_t)b*Nsz + n];
    const int i = n & (Isz-1);
    const int hw = n >> 5;
    const int wcol = hw % Ssz, hrow = hw / Ssz;
    const float ch = (hrow + 0.5f) * (1.0f/Ssz);
    const float cw = (wcol + 0.5f) * (1.0f/Ssz);

    float zz[Csz];
#pragma unroll
    for (int c = 0; c < Csz; ++c) {
        const float* Wi = &Wl[i*161 + c*16];
        const float* pc = &prm[c*33];       // broadcast reads (same addr all lanes)
        float quad = 0.f;
#pragma unroll
        for (int pr = 0; pr < 4; ++pr) {
#pragma unroll
            for (int r = 0; r < 4; ++r) {
                float v = p[pr*4+0]*Wi[0*4+r] + p[pr*4+1]*Wi[1*4+r]
                        + p[pr*4+2]*Wi[2*4+r] + p[pr*4+3]*Wi[3*4+r];
                const int d = pr*4 + r;
                if (d == 0) v += ch;
                if (d == 1) v += cw;
                float dv = v - pc[d];
                quad += dv * dv * pc[16+d];
            }
        }
        zz[c] = pc[32] - quad;
    }

    float zmax = zz[0];
#pragma unroll
    for (int c = 1; c < Csz; ++c) zmax = fmaxf(zmax, zz[c]);
    float zsum = 0.f;
#pragma unroll
    for (int c = 0; c < Csz; ++c) { zz[c] = expf(zz[c] - zmax); zsum += zz[c]; }
    const float sc = a / zsum;
#pragma unroll
    for (int c = 0; c < Csz; ++c)
        rr_p[((size_t)b*Csz + c)*Nsz + n] = zz[c] * sc;
}

// ---------------------------------------------------------------------------
// 3 routing iterations = (M0p,fin0), E1, (M1p,fin1), E2, (M2p,fin2->out).
// Workspace: rr_p [B][C][N] 16.06 MB + partials [640][8][33] 676 KB +
// params [640][33] 84 KB. Everything read from ws is written first.
// ---------------------------------------------------------------------------
extern "C" void kernel_launch(void* const* d_in, const int* in_sizes, int n_in,
                              void* d_out, int out_size, void* d_ws, size_t ws_size,
                              hipStream_t stream)
{
    const float* pose = (const float*)d_in[0];
    const float* act  = (const float*)d_in[1];
    const float* w    = (const float*)d_in[2];
    const float* bv   = (const float*)d_in[3];
    const float* ba   = (const float*)d_in[4];
    float* out = (float*)d_out;

    float* rr_p     = (float*)d_ws;
    float* partials = rr_p + (size_t)Bsz*Csz*Nsz;
    float* params   = partials + (size_t)Bsz*Csz*NCH*33;

    dim3 mgrid(Bsz*Csz, NCH);           // bc fast -> same-chunk c-blocks co-resident
    dim3 egrid((Nsz + 255)/256, Bsz);
    dim3 fgrid((Bsz*Csz + 63)/64);

    // it=0, inv_temp=1, uniform rr
    m_partial_kernel<<<mgrid, 256, 0, stream>>>(pose, act, w, rr_p, partials, 1);
    m_finalize_kernel<<<fgrid, 64, 0, stream>>>(partials, bv, ba, params, out, 1.0f, 0);
    // it=1
    e_step_kernel<<<egrid, 256, 0, stream>>>(pose, act, w, params, rr_p);
    m_partial_kernel<<<mgrid, 256, 0, stream>>>(pose, act, w, rr_p, partials, 0);
    m_finalize_kernel<<<fgrid, 64, 0, stream>>>(partials, bv, ba, params, out, 2.0f, 0);
    // it=2
    e_step_kernel<<<egrid, 256, 0, stream>>>(pose, act, w, params, rr_p);
    m_partial_kernel<<<mgrid, 256, 0, stream>>>(pose, act, w, rr_p, partials, 0);
    m_finalize_kernel<<<fgrid, 64, 0, stream>>>(partials, bv, ba, params, out, 3.0f, 1);
}

// Round 3
// 232.410 us; speedup vs baseline: 1.3232x; 1.3232x over previous
//
#include <hip/hip_runtime.h>
#include <math.h>

// Problem constants (fixed by the reference).
#define Bsz 64
#define Ssz 14
#define Isz 32
#define Csz 10
#define Psz 4
#define Dsz 16
#define Nsz (Ssz*Ssz*Isz)   // 6272
#define EPSF 1e-9f

#define NCH 8               // n-chunks for the M-step split
#define CHUNK 784           // 8*784 == 6272 exactly

// ---------------------------------------------------------------------------
// M-step partial kernel v3: block = (b, chunk), 640 threads = 10 waves,
// wave w owns class c=w. All 10 waves stream the SAME pose chunk from global
// -> 9/10 reads are same-XCD L2 hits (chunk pose = 50KB; ~3.2MB/XCD total).
// Each wave accumulates S0, S1[16], S2[16] in registers over 12.25
// iterations, then ONE 64-lane butterfly -> partials[bc][chunk][33].
// This gives 10x pose reuse (Round-2 failure: c-blocks landed on different
// XCDs, FETCH stuck at 107MB) while keeping Round-1's per-reduction
// amortization.
// ---------------------------------------------------------------------------
__global__ __launch_bounds__(640) void m_partial_kernel(
    const float* __restrict__ pose,     // [B][N][16]
    const float* __restrict__ act,      // [B][N]
    const float* __restrict__ w,        // [I][C][16]
    const float* __restrict__ rr_p,     // [B][C][N]
    float* __restrict__ partials,       // [B*C][NCH][33]
    int uniform)
{
    const int b = blockIdx.x;
    const int chunk = blockIdx.y;
    const int tid = threadIdx.x;
    const int wave = tid >> 6;          // = class c
    const int lane = tid & 63;

    __shared__ float Wm[Csz][Isz*17];   // [c][i*17+q]; 17 coprime 32 -> no conflicts

    for (int t = tid; t < Csz*Isz*Dsz; t += 640) {
        int c = t >> 9;                 // t / 512
        int rem = t & 511;
        int i = rem >> 4, q = rem & 15;
        Wm[c][i*17 + q] = w[(i*Csz + c)*Dsz + q];
    }
    __syncthreads();

    const int c = wave;
    float s0 = 0.f;
    float s1[Dsz], s2[Dsz];
#pragma unroll
    for (int d = 0; d < Dsz; ++d) { s1[d] = 0.f; s2[d] = 0.f; }

    const float* poseb = pose + (size_t)b * Nsz * Dsz;
    const float* actb  = act  + (size_t)b * Nsz;
    const float* rrb   = rr_p + ((size_t)b * Csz + c) * Nsz;
    const float* Wc    = &Wm[c][0];

    const int n_end = chunk*CHUNK + CHUNK;
    for (int n = chunk*CHUNK + lane; n < n_end; n += 64) {
        const float4* pp = reinterpret_cast<const float4*>(poseb + (size_t)n * Dsz);
        float4 a0 = pp[0], a1 = pp[1], a2 = pp[2], a3 = pp[3];
        float p[16] = {a0.x,a0.y,a0.z,a0.w, a1.x,a1.y,a1.z,a1.w,
                       a2.x,a2.y,a2.z,a2.w, a3.x,a3.y,a3.z,a3.w};
        int i  = n & (Isz-1);
        int hw = n >> 5;
        int wcol = hw % Ssz, hrow = hw / Ssz;
        float wgt = uniform ? (actb[n] * (1.0f/Csz)) : rrb[n];

        const float* Wi = &Wc[i*17];
        float v[16];
#pragma unroll
        for (int pr = 0; pr < 4; ++pr) {
#pragma unroll
            for (int r = 0; r < 4; ++r) {
                v[pr*4+r] = p[pr*4+0]*Wi[0*4+r] + p[pr*4+1]*Wi[1*4+r]
                          + p[pr*4+2]*Wi[2*4+r] + p[pr*4+3]*Wi[3*4+r];
            }
        }
        v[0] += (hrow + 0.5f) * (1.0f/Ssz);   // coordinate addition (h on elem 0)
        v[1] += (wcol + 0.5f) * (1.0f/Ssz);   // (w on elem 1)

        s0 += wgt;
#pragma unroll
        for (int d = 0; d < Dsz; ++d) {
            float wv = wgt * v[d];
            s1[d] += wv;
            s2[d] += wv * v[d];
        }
    }

    // one 64-lane wave butterfly per (b,c,chunk)
#pragma unroll
    for (int m = 32; m >= 1; m >>= 1) {
        s0 += __shfl_xor(s0, m);
#pragma unroll
        for (int d = 0; d < Dsz; ++d) {
            s1[d] += __shfl_xor(s1[d], m);
            s2[d] += __shfl_xor(s2[d], m);
        }
    }
    if (lane == 0) {
        float* pt = partials + ((size_t)(b*Csz + c)*NCH + chunk)*33;
        pt[0] = s0;
#pragma unroll
        for (int d = 0; d < Dsz; ++d) { pt[1+d] = s1[d]; pt[17+d] = s2[d]; }
    }
}

// ---------------------------------------------------------------------------
// M finalize: one thread per (b,c). Sum the NCH chunk-partials, compute
// mean/var/stdv/cost/o_act, write 33 params for the E-step; final iteration
// also writes the kernel outputs.
// ---------------------------------------------------------------------------
__global__ __launch_bounds__(64) void m_finalize_kernel(
    const float* __restrict__ partials, // [B*C][NCH][33]
    const float* __restrict__ beta_v,   // [C]
    const float* __restrict__ beta_a,   // [C]
    float* __restrict__ params,         // [B*C][33] : mean[16], invdenom[16], K
    float* __restrict__ out,            // [B][C][16] then [B][C]
    float inv_temp, int final_it)
{
    const int bc = blockIdx.x * 64 + threadIdx.x;
    if (bc >= Bsz*Csz) return;
    const int c = bc % Csz;

    float S[33];
#pragma unroll
    for (int j = 0; j < 33; ++j) S[j] = 0.f;
    const float* pb = partials + (size_t)bc * NCH * 33;
    for (int ch = 0; ch < NCH; ++ch)
#pragma unroll
        for (int j = 0; j < 33; ++j) S[j] += pb[ch*33 + j];

    float S0 = S[0];
    float rS0 = 1.f / S0;
    float sumlog = 0.f;
    float mean[16], invd[16];
#pragma unroll
    for (int d = 0; d < Dsz; ++d) {
        float S1 = S[1+d], S2 = S[17+d];
        float mn  = S1 * rS0;
        float var = fmaxf(S2 * rS0 - mn*mn, 0.f);  // one-pass variance, clamped
        float stdv = sqrtf(var);
        sumlog += __logf(stdv + EPSF);
        mean[d] = mn;
        invd[d] = 1.f / (2.f*var + EPSF);
    }
    float cost = S0 * (16.f * beta_v[c] + sumlog);
    float oact = 1.f / (1.f + __expf(-inv_temp * (beta_a[c] - cost)));

    float* prm = params + (size_t)bc * 33;
#pragma unroll
    for (int d = 0; d < Dsz; ++d) { prm[d] = mean[d]; prm[16+d] = invd[d]; }
    prm[32] = __logf(oact + EPSF) - sumlog;   // K[c] for the E-step

    if (final_it) {
        float* om = out + (size_t)bc * Dsz;
#pragma unroll
        for (int d = 0; d < Dsz; ++d) om[d] = mean[d];
        out[Bsz*Csz*Dsz + bc] = oact;
    }
}

// ---------------------------------------------------------------------------
// E-step kernel: thread per (b,n). Recompute all C*16 votes,
// zz[c] = K[c] - sum_d (v-mean)^2*invdenom, softmax over c, write
// rr_p[b][c][n] = softmax(zz)[c]*act[n]. Fast intrinsics (__expf) this
// round; error budget is 1.4e-2 vs current 3e-5.
// ---------------------------------------------------------------------------
__global__ __launch_bounds__(256) void e_step_kernel(
    const float* __restrict__ pose,     // [B][N][16]
    const float* __restrict__ act,      // [B][N]
    const float* __restrict__ w,        // [I][C][16]
    const float* __restrict__ params,   // [B*C][33]
    float* __restrict__ rr_p)           // [B][C][N]
{
    const int b = blockIdx.y;
    const int tid = threadIdx.x;
    const int n = blockIdx.x * 256 + tid;

    __shared__ float Wl[Isz*161];       // W[i][c*16+qr], stride 161 -> conflict-free
    __shared__ float prm[Csz*33];

    for (int t = tid; t < Isz*Csz*Dsz; t += 256) {
        int i = t / (Csz*Dsz);
        int rest = t - i*(Csz*Dsz);
        Wl[i*161 + rest] = w[t];
    }
    for (int t = tid; t < Csz*33; t += 256)
        prm[t] = params[(size_t)b*Csz*33 + t];
    __syncthreads();

    if (n >= Nsz) return;

    const float4* pp = reinterpret_cast<const float4*>(pose + ((size_t)b * Nsz + n) * Dsz);
    float4 a0 = pp[0], a1 = pp[1], a2 = pp[2], a3 = pp[3];
    float p[16] = {a0.x,a0.y,a0.z,a0.w, a1.x,a1.y,a1.z,a1.w,
                   a2.x,a2.y,a2.z,a2.w, a3.x,a3.y,a3.z,a3.w};
    float a = act[(size_t)b*Nsz + n];
    const int i = n & (Isz-1);
    const int hw = n >> 5;
    const int wcol = hw % Ssz, hrow = hw / Ssz;
    const float ch = (hrow + 0.5f) * (1.0f/Ssz);
    const float cw = (wcol + 0.5f) * (1.0f/Ssz);

    float zz[Csz];
#pragma unroll
    for (int c = 0; c < Csz; ++c) {
        const float* Wi = &Wl[i*161 + c*16];
        const float* pc = &prm[c*33];       // broadcast reads (same addr all lanes)
        float quad = 0.f;
#pragma unroll
        for (int pr = 0; pr < 4; ++pr) {
#pragma unroll
            for (int r = 0; r < 4; ++r) {
                float v = p[pr*4+0]*Wi[0*4+r] + p[pr*4+1]*Wi[1*4+r]
                        + p[pr*4+2]*Wi[2*4+r] + p[pr*4+3]*Wi[3*4+r];
                const int d = pr*4 + r;
                if (d == 0) v += ch;
                if (d == 1) v += cw;
                float dv = v - pc[d];
                quad += dv * dv * pc[16+d];
            }
        }
        zz[c] = pc[32] - quad;
    }

    float zmax = zz[0];
#pragma unroll
    for (int c = 1; c < Csz; ++c) zmax = fmaxf(zmax, zz[c]);
    float zsum = 0.f;
#pragma unroll
    for (int c = 0; c < Csz; ++c) { zz[c] = __expf(zz[c] - zmax); zsum += zz[c]; }
    const float sc = __fdividef(a, zsum);
#pragma unroll
    for (int c = 0; c < Csz; ++c)
        rr_p[((size_t)b*Csz + c)*Nsz + n] = zz[c] * sc;
}

// ---------------------------------------------------------------------------
// 3 routing iterations = (M0p,fin0), E1, (M1p,fin1), E2, (M2p,fin2->out).
// Workspace: rr_p [B][C][N] 16.06 MB + partials [640][8][33] 676 KB +
// params [640][33] 84 KB. Everything read from ws is written first.
// ---------------------------------------------------------------------------
extern "C" void kernel_launch(void* const* d_in, const int* in_sizes, int n_in,
                              void* d_out, int out_size, void* d_ws, size_t ws_size,
                              hipStream_t stream)
{
    const float* pose = (const float*)d_in[0];
    const float* act  = (const float*)d_in[1];
    const float* w    = (const float*)d_in[2];
    const float* bv   = (const float*)d_in[3];
    const float* ba   = (const float*)d_in[4];
    float* out = (float*)d_out;

    float* rr_p     = (float*)d_ws;
    float* partials = rr_p + (size_t)Bsz*Csz*Nsz;
    float* params   = partials + (size_t)Bsz*Csz*NCH*33;

    dim3 mgrid(Bsz, NCH);               // block = (b, chunk); 10 waves = 10 classes
    dim3 egrid((Nsz + 255)/256, Bsz);
    dim3 fgrid((Bsz*Csz + 63)/64);

    // it=0, inv_temp=1, uniform rr
    m_partial_kernel<<<mgrid, 640, 0, stream>>>(pose, act, w, rr_p, partials, 1);
    m_finalize_kernel<<<fgrid, 64, 0, stream>>>(partials, bv, ba, params, out, 1.0f, 0);
    // it=1
    e_step_kernel<<<egrid, 256, 0, stream>>>(pose, act, w, params, rr_p);
    m_partial_kernel<<<mgrid, 640, 0, stream>>>(pose, act, w, rr_p, partials, 0);
    m_finalize_kernel<<<fgrid, 64, 0, stream>>>(partials, bv, ba, params, out, 2.0f, 0);
    // it=2
    e_step_kernel<<<egrid, 256, 0, stream>>>(pose, act, w, params, rr_p);
    m_partial_kernel<<<mgrid, 640, 0, stream>>>(pose, act, w, rr_p, partials, 0);
    m_finalize_kernel<<<fgrid, 64, 0, stream>>>(partials, bv, ba, params, out, 3.0f, 1);
}

// Round 4
// 226.224 us; speedup vs baseline: 1.3593x; 1.0273x over previous
//
#include <hip/hip_runtime.h>
#include <math.h>

// Problem constants (fixed by the reference).
#define Bsz 64
#define Ssz 14
#define Isz 32
#define Csz 10
#define Dsz 16
#define Nsz (Ssz*Ssz*Isz)   // 6272
#define EPSF 1e-9f

#define CH  640             // n's per chunk == block size (one E-shot per thread)
#define NCH 10              // ceil(6272/640); chunk 9 has 512 valid n

// ---------------------------------------------------------------------------
// vote = pose(4x4) @ W[i,c](4x4) + coordinate addition on elems 0,1
// ---------------------------------------------------------------------------
__device__ __forceinline__ void compute_vote(const float* __restrict__ p,
                                             const float* __restrict__ Wi,
                                             float chh, float cww, float* v)
{
#pragma unroll
    for (int pr = 0; pr < 4; ++pr)
#pragma unroll
        for (int r = 0; r < 4; ++r)
            v[pr*4+r] = p[pr*4+0]*Wi[0*4+r] + p[pr*4+1]*Wi[1*4+r]
                      + p[pr*4+2]*Wi[2*4+r] + p[pr*4+3]*Wi[3*4+r];
    v[0] += chh;
    v[1] += cww;
}

// ---------------------------------------------------------------------------
// M0: uniform-rr M-step partials. Block=(b,chunk), 640 thr = 10 waves,
// wave c accumulates S0,S1[16],S2[16] over the chunk with w_n = act[n]/C,
// one 64-lane butterfly, write partials[bc][chunk][33].
// ---------------------------------------------------------------------------
__global__ __launch_bounds__(640) void m0_kernel(
    const float* __restrict__ pose,     // [B][N][16]
    const float* __restrict__ act,      // [B][N]
    const float* __restrict__ w,        // [I][C][16]
    float* __restrict__ partials)       // [B*C][NCH][33]
{
    const int b = blockIdx.x, chunk = blockIdx.y;
    const int tid = threadIdx.x, c = tid >> 6, lane = tid & 63;

    __shared__ float Wm[Csz][Isz*17];   // stride 17 (coprime 32) -> conflict-free

    for (int t = tid; t < Csz*Isz*Dsz; t += 640) {
        int cc = t >> 9, rem = t & 511, i = rem >> 4, q = rem & 15;
        Wm[cc][i*17 + q] = w[(i*Csz + cc)*Dsz + q];
    }
    __syncthreads();

    float s0 = 0.f, s1[Dsz], s2[Dsz];
#pragma unroll
    for (int d = 0; d < Dsz; ++d) { s1[d] = 0.f; s2[d] = 0.f; }

    const float* poseb = pose + (size_t)b * Nsz * Dsz;
    const float* actb  = act  + (size_t)b * Nsz;
    const int base = chunk * CH;

    for (int nl = lane; nl < CH; nl += 64) {
        const int n = base + nl;
        if (n < Nsz) {
            const float4* pp = reinterpret_cast<const float4*>(poseb + (size_t)n * Dsz);
            float4 a0 = pp[0], a1 = pp[1], a2 = pp[2], a3 = pp[3];
            float p[16] = {a0.x,a0.y,a0.z,a0.w, a1.x,a1.y,a1.z,a1.w,
                           a2.x,a2.y,a2.z,a2.w, a3.x,a3.y,a3.z,a3.w};
            int i = n & 31, hw = n >> 5;
            int wc = hw % Ssz, hr = hw / Ssz;
            float wgt = actb[n] * (1.0f/Csz);
            float v[16];
            compute_vote(p, &Wm[c][i*17], (hr+0.5f)*(1.0f/Ssz), (wc+0.5f)*(1.0f/Ssz), v);
            s0 += wgt;
#pragma unroll
            for (int d = 0; d < Dsz; ++d) {
                float wv = wgt * v[d];
                s1[d] += wv;
                s2[d] += wv * v[d];
            }
        }
    }

#pragma unroll
    for (int m = 32; m >= 1; m >>= 1) {
        s0 += __shfl_xor(s0, m);
#pragma unroll
        for (int d = 0; d < Dsz; ++d) {
            s1[d] += __shfl_xor(s1[d], m);
            s2[d] += __shfl_xor(s2[d], m);
        }
    }
    if (lane == 0) {
        float* pt = partials + ((size_t)(b*Csz + c)*NCH + chunk)*33;
        pt[0] = s0;
#pragma unroll
        for (int d = 0; d < Dsz; ++d) { pt[1+d] = s1[d]; pt[17+d] = s2[d]; }
    }
}

// ---------------------------------------------------------------------------
// Fused finalize(prev M) + E + M kernel. Block=(b,chunk), 640 threads.
//  phase F: redundantly reduce prev partials for this b -> params in LDS
//           (mean[16], invd[16], K) -- removes finalize dispatches + global
//           params round-trip.
//  phase E: thread-per-n: votes for all 10 c, zz, softmax, rr*act -> LDS.
//  phase M: wave c accumulates S0/S1/S2 from LDS rr + recomputed votes;
//           butterfly -> part_out. rr never touches global memory.
// Double-buffered partials (in != out) since blocks of the same b read all
// chunks' partials while others write theirs.
// ---------------------------------------------------------------------------
__global__ __launch_bounds__(640) void em_kernel(
    const float* __restrict__ pose,     // [B][N][16]
    const float* __restrict__ act,      // [B][N]
    const float* __restrict__ w,        // [I][C][16]
    const float* __restrict__ beta_v,   // [C]
    const float* __restrict__ beta_a,   // [C]
    const float* __restrict__ part_in,  // [B*C][NCH][33]
    float* __restrict__ part_out,       // [B*C][NCH][33]
    float inv_temp_prev)
{
    const int b = blockIdx.x, chunk = blockIdx.y;
    const int tid = threadIdx.x, wv = tid >> 6, lane = tid & 63;

    __shared__ float Wm[Csz][Isz*17];   // 21760 B
    __shared__ float rr[Csz][CH];       // 25600 B
    __shared__ float prm[Csz][33];      // mean16, invd16, K
    __shared__ float Sv[Csz][33];
    __shared__ float lg[Csz][16];

    // ---- stage W + reduce prev partials for this b ----
    for (int t = tid; t < Csz*Isz*Dsz; t += 640) {
        int cc = t >> 9, rem = t & 511, i = rem >> 4, q = rem & 15;
        Wm[cc][i*17 + q] = w[(i*Csz + cc)*Dsz + q];
    }
    if (tid < Csz*33) {
        int c = tid / 33, j = tid - c*33;
        const float* pp = part_in + ((size_t)(b*Csz + c)*NCH)*33 + j;
        float s = 0.f;
        for (int ch2 = 0; ch2 < NCH; ++ch2) s += pp[ch2*33];
        Sv[c][j] = s;
    }
    __syncthreads();
    if (tid < Csz*Dsz) {
        int c = tid >> 4, d = tid & 15;
        float S0 = Sv[c][0];
        float mn  = Sv[c][1+d] / S0;
        float var = fmaxf(Sv[c][17+d] / S0 - mn*mn, 0.f);
        float stdv = sqrtf(var);
        prm[c][d]    = mn;
        prm[c][16+d] = 1.f / (2.f*var + EPSF);
        lg[c][d]     = __logf(stdv + EPSF);
    }
    __syncthreads();
    if (tid < Csz) {
        int c = tid;
        float sumlog = 0.f;
#pragma unroll
        for (int d = 0; d < Dsz; ++d) sumlog += lg[c][d];
        float cost = Sv[c][0] * (16.f * beta_v[c] + sumlog);
        float oact = 1.f / (1.f + __expf(-inv_temp_prev * (beta_a[c] - cost)));
        prm[c][32] = __logf(oact + EPSF) - sumlog;    // K[c]
    }
    __syncthreads();

    // ---- E phase: one n per thread ----
    const int base = chunk * CH;
    const float* poseb = pose + (size_t)b * Nsz * Dsz;
    {
        const int n = base + tid;
        if (n < Nsz) {
            const float4* pp = reinterpret_cast<const float4*>(poseb + (size_t)n * Dsz);
            float4 a0 = pp[0], a1 = pp[1], a2 = pp[2], a3 = pp[3];
            float p[16] = {a0.x,a0.y,a0.z,a0.w, a1.x,a1.y,a1.z,a1.w,
                           a2.x,a2.y,a2.z,a2.w, a3.x,a3.y,a3.z,a3.w};
            int i = n & 31, hw = n >> 5;
            int wc = hw % Ssz, hr = hw / Ssz;
            float chh = (hr+0.5f)*(1.0f/Ssz), cww = (wc+0.5f)*(1.0f/Ssz);
            float a = act[(size_t)b*Nsz + n];

            float zz[Csz];
#pragma unroll
            for (int c = 0; c < Csz; ++c) {
                float v[16];
                compute_vote(p, &Wm[c][i*17], chh, cww, v);
                float quad = 0.f;
#pragma unroll
                for (int d = 0; d < Dsz; ++d) {
                    float dv = v[d] - prm[c][d];
                    quad += dv * dv * prm[c][16+d];
                }
                zz[c] = prm[c][32] - quad;
            }
            float zmax = zz[0];
#pragma unroll
            for (int c = 1; c < Csz; ++c) zmax = fmaxf(zmax, zz[c]);
            float zsum = 0.f;
#pragma unroll
            for (int c = 0; c < Csz; ++c) { zz[c] = __expf(zz[c] - zmax); zsum += zz[c]; }
            float sc = __fdividef(a, zsum);
#pragma unroll
            for (int c = 0; c < Csz; ++c) rr[c][tid] = zz[c] * sc;
        }
    }
    __syncthreads();

    // ---- M phase: wave wv = class ----
    const int c = wv;
    float s0 = 0.f, s1[Dsz], s2[Dsz];
#pragma unroll
    for (int d = 0; d < Dsz; ++d) { s1[d] = 0.f; s2[d] = 0.f; }

    for (int nl = lane; nl < CH; nl += 64) {
        const int n = base + nl;
        if (n < Nsz) {
            const float4* pp = reinterpret_cast<const float4*>(poseb + (size_t)n * Dsz);
            float4 a0 = pp[0], a1 = pp[1], a2 = pp[2], a3 = pp[3];
            float p[16] = {a0.x,a0.y,a0.z,a0.w, a1.x,a1.y,a1.z,a1.w,
                           a2.x,a2.y,a2.z,a2.w, a3.x,a3.y,a3.z,a3.w};
            int i = n & 31, hw = n >> 5;
            int wc = hw % Ssz, hr = hw / Ssz;
            float wgt = rr[c][nl];
            float v[16];
            compute_vote(p, &Wm[c][i*17], (hr+0.5f)*(1.0f/Ssz), (wc+0.5f)*(1.0f/Ssz), v);
            s0 += wgt;
#pragma unroll
            for (int d = 0; d < Dsz; ++d) {
                float wvv = wgt * v[d];
                s1[d] += wvv;
                s2[d] += wvv * v[d];
            }
        }
    }

#pragma unroll
    for (int m = 32; m >= 1; m >>= 1) {
        s0 += __shfl_xor(s0, m);
#pragma unroll
        for (int d = 0; d < Dsz; ++d) {
            s1[d] += __shfl_xor(s1[d], m);
            s2[d] += __shfl_xor(s2[d], m);
        }
    }
    if (lane == 0) {
        float* pt = part_out + ((size_t)(b*Csz + c)*NCH + chunk)*33;
        pt[0] = s0;
#pragma unroll
        for (int d = 0; d < Dsz; ++d) { pt[1+d] = s1[d]; pt[17+d] = s2[d]; }
    }
}

// ---------------------------------------------------------------------------
// Final finalize: thread per (b,c): reduce last partials, compute mean +
// o_act with inv_temp=3, write outputs.
// ---------------------------------------------------------------------------
__global__ __launch_bounds__(64) void fin_kernel(
    const float* __restrict__ partials, // [B*C][NCH][33]
    const float* __restrict__ beta_v,
    const float* __restrict__ beta_a,
    float* __restrict__ out,            // [B][C][16] then [B][C]
    float inv_temp)
{
    const int bc = blockIdx.x * 64 + threadIdx.x;
    if (bc >= Bsz*Csz) return;
    const int c = bc % Csz;

    float S[33];
#pragma unroll
    for (int j = 0; j < 33; ++j) S[j] = 0.f;
    const float* pb = partials + (size_t)bc * NCH * 33;
    for (int ch2 = 0; ch2 < NCH; ++ch2)
#pragma unroll
        for (int j = 0; j < 33; ++j) S[j] += pb[ch2*33 + j];

    float S0 = S[0], rS0 = 1.f / S0;
    float sumlog = 0.f;
    float* om = out + (size_t)bc * Dsz;
#pragma unroll
    for (int d = 0; d < Dsz; ++d) {
        float mn  = S[1+d] * rS0;
        float var = fmaxf(S[17+d] * rS0 - mn*mn, 0.f);
        sumlog += __logf(sqrtf(var) + EPSF);
        om[d] = mn;
    }
    float cost = S0 * (16.f * beta_v[c] + sumlog);
    float oact = 1.f / (1.f + __expf(-inv_temp * (beta_a[c] - cost)));
    out[Bsz*Csz*Dsz + bc] = oact;
}

// ---------------------------------------------------------------------------
// 4 dispatches: M0 -> EM1(fin0+E1+M1) -> EM2(fin1+E2+M2) -> FIN(fin2->out).
// Workspace: partials A,B = 2 x 640*10*33 floats = 1.69 MB. rr lives in LDS.
// ---------------------------------------------------------------------------
extern "C" void kernel_launch(void* const* d_in, const int* in_sizes, int n_in,
                              void* d_out, int out_size, void* d_ws, size_t ws_size,
                              hipStream_t stream)
{
    const float* pose = (const float*)d_in[0];
    const float* act  = (const float*)d_in[1];
    const float* w    = (const float*)d_in[2];
    const float* bv   = (const float*)d_in[3];
    const float* ba   = (const float*)d_in[4];
    float* out = (float*)d_out;

    float* partA = (float*)d_ws;
    float* partB = partA + (size_t)Bsz*Csz*NCH*33;

    dim3 grid(Bsz, NCH);

    m0_kernel<<<grid, CH, 0, stream>>>(pose, act, w, partA);
    em_kernel<<<grid, CH, 0, stream>>>(pose, act, w, bv, ba, partA, partB, 1.0f);
    em_kernel<<<grid, CH, 0, stream>>>(pose, act, w, bv, ba, partB, partA, 2.0f);
    fin_kernel<<<(Bsz*Csz + 63)/64, 64, 0, stream>>>(partA, bv, ba, out, 3.0f);
}